// Round 5
// baseline (303.349 us; speedup 1.0000x reference)
//
#include <hip/hip_runtime.h>
#include <stdint.h>

#define BB 4
#define TT 2048
#define DD 1024
#define NX (BB*TT*DD)          /* 8388608 x elements   */
#define NW (DD*DD)             /* 1048576 per W        */
#define SCALE 0.022097086912079608f   /* 1/sqrt(2048) */

typedef short v8s __attribute__((ext_vector_type(8)));
typedef float v4f __attribute__((ext_vector_type(4)));

typedef const void __attribute__((address_space(1))) *as1_cvp;
typedef void __attribute__((address_space(3))) *as3_vp;

__device__ __forceinline__ short f2bf(float f) {
    union { float f; uint32_t u; } x; x.f = f;
    uint32_t r = x.u + 0x7fffu + ((x.u >> 16) & 1u);   // RNE, finite inputs
    return (short)(r >> 16);
}
__device__ __forceinline__ float bf2f(short s) {
    union { uint32_t u; float f; } x; x.u = ((uint32_t)(uint16_t)s) << 16;
    return x.f;
}

// Async 16B global->LDS. lds dest must be wave-uniform base + lane*16.
__device__ __forceinline__ void gl_lds16(const short* g, const short* lds_wave_base) {
    __builtin_amdgcn_global_load_lds(
        (as1_cvp)(uintptr_t)(const void*)g,
        (as3_vp)(uint32_t)(uintptr_t)(const void*)lds_wave_base,
        16, 0, 0);
}

// ---- BK=64 staging (k_pk / k_pv): 128x64 shorts, XOR-8 swizzle -------------
__device__ __forceinline__ void stage_tile(const short* __restrict__ gsrc, int lda,
                                           short* lds, int tid) {
    int wave = tid >> 6;
    #pragma unroll
    for (int is = 0; is < 4; is++) {
        int t = is * 256 + tid;          // 0..1023 : 16B chunk index
        int r = t >> 3, c = t & 7;
        int cg = c ^ (r & 7);            // swizzled global chunk
        const short* g = gsrc + (size_t)r * lda + cg * 8;
        const short* l = lds + is * 2048 + wave * 512;   // wave-uniform
        gl_lds16(g, l);
    }
}
__device__ __forceinline__ v8s frag_read(const short* lds, int row, int cg) {
    return *(const v8s*)(lds + row * 64 + ((cg ^ (row & 7)) << 3));
}
#define COMPUTE_TILE(Ac, Bc)                                                        \
    _Pragma("unroll")                                                               \
    for (int kk = 0; kk < 2; kk++) {                                                \
        v8s af[4], bf[4];                                                           \
        _Pragma("unroll")                                                           \
        for (int i = 0; i < 4; i++) af[i] = frag_read(Ac, wm + i*16 + lr, kk*4 + lq); \
        _Pragma("unroll")                                                           \
        for (int j = 0; j < 4; j++) bf[j] = frag_read(Bc, wn + j*16 + lr, kk*4 + lq); \
        _Pragma("unroll")                                                           \
        for (int i = 0; i < 4; i++)                                                 \
            _Pragma("unroll")                                                       \
            for (int j = 0; j < 4; j++)                                             \
                acc[i][j] = __builtin_amdgcn_mfma_f32_16x16x32_bf16(af[i], bf[j], acc[i][j], 0, 0, 0); \
    }

// ---- BK=32 staging (k_qkv): 128x32 shorts, XOR-4 swizzle -------------------
__device__ __forceinline__ void stage_tile32(const short* __restrict__ gsrc, int lda,
                                             short* lds, int tid) {
    int wave = tid >> 6;
    #pragma unroll
    for (int is = 0; is < 2; is++) {
        int t = is * 256 + tid;          // 0..511 : 16B chunk index
        int r = t >> 2, c = t & 3;
        int cg = c ^ (r & 3);
        const short* g = gsrc + (size_t)r * lda + cg * 8;
        const short* l = lds + is * 2048 + wave * 512;
        gl_lds16(g, l);
    }
}
__device__ __forceinline__ v8s frag_read32(const short* lds, int row, int cg) {
    return *(const v8s*)(lds + row * 32 + ((cg ^ (row & 3)) << 3));
}
#define COMPUTE_TILE32(Ac, Bc)                                                      \
    {                                                                               \
        v8s af[4], bf[4];                                                           \
        _Pragma("unroll")                                                           \
        for (int i = 0; i < 4; i++) af[i] = frag_read32(Ac, wm + i*16 + lr, lq);    \
        _Pragma("unroll")                                                           \
        for (int j = 0; j < 4; j++) bf[j] = frag_read32(Bc, wn + j*16 + lr, lq);    \
        _Pragma("unroll")                                                           \
        for (int i = 0; i < 4; i++)                                                 \
            _Pragma("unroll")                                                       \
            for (int j = 0; j < 4; j++)                                             \
                acc[i][j] = __builtin_amdgcn_mfma_f32_16x16x32_bf16(af[i], bf[j], acc[i][j], 0, 0, 0); \
    }

// k_pv split-K chunk tables: (qt, tile0, tile1), sorted big-first. 24 chunks.
__device__ __constant__ int pv_qt[24] = {15,15,14, 7,14,13,13,12, 6,12,11,11,10, 5,10, 9, 9, 8, 4, 8, 3, 2, 1, 0};
__device__ __constant__ int pv_t0[24] = { 0, 8, 0, 0, 8, 0, 7, 0, 0, 7, 0, 6, 0, 0, 6, 0, 5, 0, 0, 5, 0, 0, 0, 0};
__device__ __constant__ int pv_t1[24] = { 8,16, 8, 8,15, 7,14, 7, 7,13, 6,12, 6, 6,11, 5,10, 5, 5, 9, 4, 3, 2, 1};

// ---------------------------------------------------------------- convert (+ rowsum init + out zero)
__global__ void k_convert(const float* __restrict__ x, const float* __restrict__ Wq,
                          const float* __restrict__ Wk, const float* __restrict__ Wv,
                          short* __restrict__ dst, float* __restrict__ rowsum,
                          float* __restrict__ out) {
    int i = blockIdx.x * 256 + threadIdx.x;   // exactly (NX+3*NW)/4 threads
    if (i < BB * TT) rowsum[i] = (float)((15 - ((i & 2047) >> 7)) * 128);
    // zero-init rows t>=1024 of out (atomic-accumulated by k_pv)
    if (i < 2097152) {
        int t = (i >> 8) & 2047;
        if (t >= 1024) ((float4*)out)[i] = (float4){0.f, 0.f, 0.f, 0.f};
    }
    size_t base = (size_t)i * 4;
    const float* src; size_t off;
    if (base < NX)               { src = x;  off = base; }
    else if (base < NX + NW)     { src = Wq; off = base - NX; }
    else if (base < NX + 2*(size_t)NW) { src = Wk; off = base - NX - NW; }
    else                         { src = Wv; off = base - NX - 2*(size_t)NW; }
    float4 f = *(const float4*)(src + off);
    short4 h; h.x = f2bf(f.x); h.y = f2bf(f.y); h.z = f2bf(f.z); h.w = f2bf(f.w);
    *(short4*)(dst + base) = h;
}

// ---------------------------------------------------------------- QKV GEMM (BK=32 dbuf)
__global__ __launch_bounds__(256) void k_qkv(const short* __restrict__ xb,
                                             const short* __restrict__ wb,
                                             short* __restrict__ q,
                                             short* __restrict__ k,
                                             short* __restrict__ vt) {
    int which = blockIdx.z;
    const short* Bm = wb + (size_t)which * NW;
    int m0 = blockIdx.x * 128, n0 = blockIdx.y * 128;
    __shared__ __align__(16) short SH[16384];   // A0|A1|B0|B1, 8KB each
    int tid = threadIdx.x, lane = tid & 63, wave = tid >> 6;
    int wm = (wave >> 1) * 64, wn = (wave & 1) * 64;
    int lr = lane & 15, lq = lane >> 4;
    v4f acc[4][4];
    for (int i = 0; i < 4; i++) for (int j = 0; j < 4; j++) acc[i][j] = (v4f){0.f,0.f,0.f,0.f};

    const short* Ag = xb + (size_t)m0 * 1024;
    const short* Bg = Bm + (size_t)n0 * 1024;
    stage_tile32(Ag, 1024, SH, tid);
    stage_tile32(Bg, 1024, SH + 8192, tid);
    for (int it = 0; it < 32; ++it) {
        __syncthreads();                       // drains cur-buffer loads
        int cur = (it & 1) * 4096;
        short* Ac = SH + cur;
        short* Bc = SH + 8192 + cur;
        if (it + 1 < 32) {                     // prefetch next tile pair
            int nxt = ((it + 1) & 1) * 4096;
            stage_tile32(Ag + (it + 1) * 32, 1024, SH + nxt, tid);
            stage_tile32(Bg + (it + 1) * 32, 1024, SH + 8192 + nxt, tid);
        }
        COMPUTE_TILE32(Ac, Bc);
    }
    short* outp = (which == 0) ? q : k;
    #pragma unroll
    for (int i = 0; i < 4; i++)
        #pragma unroll
        for (int j = 0; j < 4; j++)
            #pragma unroll
            for (int r = 0; r < 4; r++) {
                int row = m0 + wm + i*16 + lq*4 + r;     // m = b*2048+t
                int col = n0 + wn + j*16 + lr;           // e
                short hv = f2bf(acc[i][j][r]);
                if (which == 2) {
                    int bb = row >> 11, t = row & 2047;
                    vt[((size_t)bb << 21) + ((size_t)col << 11) + t] = hv;
                } else {
                    outp[(size_t)row * 1024 + col] = hv;
                }
            }
}

// ---------------------------------------------------------------- tile suffix sums
__global__ void k_ts1(const short* __restrict__ vt, float* __restrict__ TSpart) {
    int g = blockIdx.x * 256 + threadIdx.x;           // 4*16*1024 threads
    int b = g >> 14, jt = (g >> 10) & 15, e = g & 1023;
    const short* row = vt + ((size_t)b << 21) + ((size_t)e << 11) + jt * 128;
    float s = 0.f;
    #pragma unroll
    for (int c = 0; c < 16; c++) {
        uint4 u = *(const uint4*)(row + c * 8);
        const short* hp = (const short*)&u;
        #pragma unroll
        for (int z = 0; z < 8; z++) s += bf2f(hp[z]);
    }
    TSpart[g] = s;   // [b][jt][e]
}
__global__ void k_ts2(const float* __restrict__ TSpart, float* __restrict__ TS) {
    int g = blockIdx.x * 256 + threadIdx.x;           // 4*1024 threads
    int b = g >> 10, e = g & 1023;
    float acc = 0.f;
    TS[(size_t)(b * 17 + 16) * 1024 + e] = 0.f;
    for (int jt = 15; jt >= 0; jt--) {
        acc += TSpart[(size_t)(b * 16 + jt) * 1024 + e];
        TS[(size_t)(b * 17 + jt) * 1024 + e] = acc;   // sum over j >= jt*128
    }
}

// ---------------------------------------------------------------- S -> P kernel (dbuf, compact grid)
__global__ __launch_bounds__(256) void k_pk(const short* __restrict__ qm,
                                            const short* __restrict__ km,
                                            short* __restrict__ P,
                                            float* __restrict__ rowsum) {
    int idx = blockIdx.x, b = blockIdx.z;
    int qt = 0;
    while ((qt + 1) * (qt + 2) / 2 <= idx) qt++;
    int kt = idx - qt * (qt + 1) / 2;
    const short* Ag = qm + ((size_t)b * 2048 + (size_t)qt * 128) * 1024;
    const short* Bg = km + ((size_t)b * 2048 + (size_t)kt * 128) * 1024;
    __shared__ __align__(16) short SH[32768];
    int tid = threadIdx.x, lane = tid & 63, wave = tid >> 6;
    int wm = (wave >> 1) * 64, wn = (wave & 1) * 64;
    int lr = lane & 15, lq = lane >> 4;
    v4f acc[4][4];
    for (int i = 0; i < 4; i++) for (int j = 0; j < 4; j++) acc[i][j] = (v4f){0.f,0.f,0.f,0.f};

    stage_tile(Ag, 1024, SH, tid);
    stage_tile(Bg, 1024, SH + 16384, tid);
    for (int it = 0; it < 16; ++it) {
        __syncthreads();
        int cur = (it & 1) * 8192;
        short* Ac = SH + cur;
        short* Bc = SH + 16384 + cur;
        if (it + 1 < 16) {
            int nxt = ((it + 1) & 1) * 8192;
            stage_tile(Ag + (it + 1) * 64, 1024, SH + nxt, tid);
            stage_tile(Bg + (it + 1) * 64, 1024, SH + 16384 + nxt, tid);
        }
        COMPUTE_TILE(Ac, Bc);
    }
    short* Pb = P + ((size_t)b << 22);
    float rs[4][4];
    for (int i = 0; i < 4; i++) for (int r = 0; r < 4; r++) rs[i][r] = 0.f;
    #pragma unroll
    for (int i = 0; i < 4; i++)
        #pragma unroll
        for (int j = 0; j < 4; j++)
            #pragma unroll
            for (int r = 0; r < 4; r++) {
                int qi = qt * 128 + wm + i*16 + lq*4 + r;
                int kj = kt * 128 + wn + j*16 + lr;
                float p = (kj <= qi) ? __expf(acc[i][j][r] * SCALE) : 1.0f;
                Pb[(size_t)qi * 2048 + kj] = f2bf(p);
                rs[i][r] += p;
            }
    #pragma unroll
    for (int m = 1; m < 16; m <<= 1)
        #pragma unroll
        for (int i = 0; i < 4; i++)
            #pragma unroll
            for (int r = 0; r < 4; r++) rs[i][r] += __shfl_xor(rs[i][r], m);
    if (lr == 0)
        #pragma unroll
        for (int i = 0; i < 4; i++)
            #pragma unroll
            for (int r = 0; r < 4; r++)
                atomicAdd(&rowsum[b * 2048 + qt * 128 + wm + i*16 + lq*4 + r], rs[i][r]);
}

// ---------------------------------------------------------------- PV kernel (split-K, dbuf)
__global__ __launch_bounds__(256) void k_pv(const short* __restrict__ P,
                                            const short* __restrict__ vt,
                                            const float* __restrict__ rowsum,
                                            const float* __restrict__ TS,
                                            float* __restrict__ out) {
    int c = blockIdx.x, et = blockIdx.y, b = blockIdx.z;
    int qt = pv_qt[c], t0 = pv_t0[c], t1 = pv_t1[c];
    bool last  = (t1 == qt + 1);           // this chunk adds the TS term
    bool single = (t0 == 0) && last;       // sole chunk for this row-block
    const short* Ag = P  + ((size_t)b << 22) + (size_t)qt * 128 * 2048 + t0 * 128;
    const short* Bg = vt + ((size_t)b << 21) + (size_t)et * 128 * 2048 + t0 * 128;
    int iters = 2 * (t1 - t0);
    __shared__ __align__(16) short SH[32768];
    int tid = threadIdx.x, lane = tid & 63, wave = tid >> 6;
    int wm = (wave >> 1) * 64, wn = (wave & 1) * 64;
    int lr = lane & 15, lq = lane >> 4;
    v4f acc[4][4];
    for (int i = 0; i < 4; i++) for (int j = 0; j < 4; j++) acc[i][j] = (v4f){0.f,0.f,0.f,0.f};

    stage_tile(Ag, 2048, SH, tid);
    stage_tile(Bg, 2048, SH + 16384, tid);
    for (int it = 0; it < iters; ++it) {
        __syncthreads();
        int cur = (it & 1) * 8192;
        short* Ac = SH + cur;
        short* Bc = SH + 16384 + cur;
        if (it + 1 < iters) {
            int nxt = ((it + 1) & 1) * 8192;
            stage_tile(Ag + (it + 1) * 64, 2048, SH + nxt, tid);
            stage_tile(Bg + (it + 1) * 64, 2048, SH + 16384 + nxt, tid);
        }
        COMPUTE_TILE(Ac, Bc);
    }
    const float* tsrow = TS + (size_t)(b * 17 + qt + 1) * 1024;
    #pragma unroll
    for (int i = 0; i < 4; i++)
        #pragma unroll
        for (int j = 0; j < 4; j++)
            #pragma unroll
            for (int r = 0; r < 4; r++) {
                int row = qt * 128 + wm + i*16 + lq*4 + r;
                int col = et * 128 + wn + j*16 + lr;
                float rs = rowsum[b * 2048 + row];
                float num = acc[i][j][r] + (last ? tsrow[col] : 0.f);
                float* dst = out + ((size_t)(b * 2048 + row) << 10) + col;
                if (single) *dst = num / rs;
                else        atomicAdd(dst, num / rs);
            }
}

// ---------------------------------------------------------------- launch
extern "C" void kernel_launch(void* const* d_in, const int* in_sizes, int n_in,
                              void* d_out, int out_size, void* d_ws, size_t ws_size,
                              hipStream_t stream) {
    const float* x  = (const float*)d_in[0];
    const float* Wq = (const float*)d_in[1];
    const float* Wk = (const float*)d_in[2];
    const float* Wv = (const float*)d_in[3];
    float* out = (float*)d_out;
    char* ws = (char*)d_ws;

    short* xb     = (short*)(ws + 0);            // 16,777,216 B
    short* wb     = (short*)(ws + 16777216);     //  6,291,456 B (Wq|Wk|Wv bf16)
    short* q      = (short*)(ws + 23068672);     // 16,777,216 B
    short* k      = (short*)(ws + 39845888);     // 16,777,216 B
    short* vt     = (short*)(ws + 56623104);     // 16,777,216 B  v transposed [b][e][t]
    short* P      = (short*)(ws + 73400320);     // 33,554,432 B
    float* rowsum = (float*)(ws + 106954752);    //     32,768 B
    float* TSpart = (float*)(ws + 106987520);    //    262,144 B
    float* TS     = (float*)(ws + 107249664);    //    278,528 B   total ~102.6 MB

    k_convert<<<11264, 256, 0, stream>>>(x, Wq, Wk, Wv, xb, rowsum, out);
    k_qkv<<<dim3(64, 8, 3), 256, 0, stream>>>(xb, wb, q, k, vt);
    k_ts1<<<256, 256, 0, stream>>>(vt, TSpart);
    k_ts2<<<16, 256, 0, stream>>>(TSpart, TS);
    k_pk<<<dim3(136, 1, 4), 256, 0, stream>>>(q, k, P, rowsum);
    k_pv<<<dim3(24, 8, 4), 256, 0, stream>>>(P, vt, rowsum, TS, out);
}

// Round 6
// 250.274 us; speedup vs baseline: 1.2121x; 1.2121x over previous
//
#include <hip/hip_runtime.h>
#include <stdint.h>

#define BB 4
#define TT 2048
#define DD 1024
#define NX (BB*TT*DD)          /* 8388608 x elements   */
#define NW (DD*DD)             /* 1048576 per W        */
#define SCALE 0.022097086912079608f   /* 1/sqrt(2048) */

typedef short v8s __attribute__((ext_vector_type(8)));
typedef float v4f __attribute__((ext_vector_type(4)));

typedef const void __attribute__((address_space(1))) *as1_cvp;
typedef void __attribute__((address_space(3))) *as3_vp;

__device__ __forceinline__ short f2bf(float f) {
    union { float f; uint32_t u; } x; x.f = f;
    uint32_t r = x.u + 0x7fffu + ((x.u >> 16) & 1u);   // RNE, finite inputs
    return (short)(r >> 16);
}
__device__ __forceinline__ float bf2f(short s) {
    union { uint32_t u; float f; } x; x.u = ((uint32_t)(uint16_t)s) << 16;
    return x.f;
}

// Async 16B global->LDS. lds dest must be wave-uniform base + lane*16.
__device__ __forceinline__ void gl_lds16(const short* g, const short* lds_wave_base) {
    __builtin_amdgcn_global_load_lds(
        (as1_cvp)(uintptr_t)(const void*)g,
        (as3_vp)(uint32_t)(uintptr_t)(const void*)lds_wave_base,
        16, 0, 0);
}

// ---- BK=64 staging: 128x64 shorts, XOR-8 swizzle (rows span all 32 banks) --
__device__ __forceinline__ void stage_tile(const short* __restrict__ gsrc, int lda,
                                           short* lds, int tid) {
    int wave = tid >> 6;
    #pragma unroll
    for (int is = 0; is < 4; is++) {
        int t = is * 256 + tid;          // 0..1023 : 16B chunk index
        int r = t >> 3, c = t & 7;
        int cg = c ^ (r & 7);            // swizzled global chunk
        const short* g = gsrc + (size_t)r * lda + cg * 8;
        const short* l = lds + is * 2048 + wave * 512;   // wave-uniform
        gl_lds16(g, l);
    }
}
__device__ __forceinline__ v8s frag_read(const short* lds, int row, int cg) {
    return *(const v8s*)(lds + row * 64 + ((cg ^ (row & 7)) << 3));
}
#define COMPUTE_TILE(Ac, Bc)                                                        \
    _Pragma("unroll")                                                               \
    for (int kk = 0; kk < 2; kk++) {                                                \
        v8s af[4], bf[4];                                                           \
        _Pragma("unroll")                                                           \
        for (int i = 0; i < 4; i++) af[i] = frag_read(Ac, wm + i*16 + lr, kk*4 + lq); \
        _Pragma("unroll")                                                           \
        for (int j = 0; j < 4; j++) bf[j] = frag_read(Bc, wn + j*16 + lr, kk*4 + lq); \
        _Pragma("unroll")                                                           \
        for (int i = 0; i < 4; i++)                                                 \
            _Pragma("unroll")                                                       \
            for (int j = 0; j < 4; j++)                                             \
                acc[i][j] = __builtin_amdgcn_mfma_f32_16x16x32_bf16(af[i], bf[j], acc[i][j], 0, 0, 0); \
    }

// ---------------------------------------------------------------- convert (+ rowsum init)
__global__ void k_convert(const float* __restrict__ x, const float* __restrict__ Wq,
                          const float* __restrict__ Wk, const float* __restrict__ Wv,
                          short* __restrict__ dst, float* __restrict__ rowsum) {
    int i = blockIdx.x * 256 + threadIdx.x;   // exactly (NX+3*NW)/4 threads
    if (i < BB * TT) rowsum[i] = (float)((15 - ((i & 2047) >> 7)) * 128);
    size_t base = (size_t)i * 4;
    const float* src; size_t off;
    if (base < NX)               { src = x;  off = base; }
    else if (base < NX + NW)     { src = Wq; off = base - NX; }
    else if (base < NX + 2*(size_t)NW) { src = Wk; off = base - NX - NW; }
    else                         { src = Wv; off = base - NX - 2*(size_t)NW; }
    float4 f = *(const float4*)(src + off);
    short4 h; h.x = f2bf(f.x); h.y = f2bf(f.y); h.z = f2bf(f.z); h.w = f2bf(f.w);
    *(short4*)(dst + base) = h;
}

// ---------------------------------------------------------------- QKV GEMM (BK=64 dbuf)
__global__ __launch_bounds__(256) void k_qkv(const short* __restrict__ xb,
                                             const short* __restrict__ wb,
                                             short* __restrict__ q,
                                             short* __restrict__ k,
                                             short* __restrict__ vt) {
    int which = blockIdx.z;
    const short* Bm = wb + (size_t)which * NW;
    int m0 = blockIdx.x * 128, n0 = blockIdx.y * 128;
    __shared__ __align__(16) short SH[32768];   // A0|A1|B0|B1, 16KB each
    int tid = threadIdx.x, lane = tid & 63, wave = tid >> 6;
    int wm = (wave >> 1) * 64, wn = (wave & 1) * 64;
    int lr = lane & 15, lq = lane >> 4;
    v4f acc[4][4];
    for (int i = 0; i < 4; i++) for (int j = 0; j < 4; j++) acc[i][j] = (v4f){0.f,0.f,0.f,0.f};

    const short* Ag = xb + (size_t)m0 * 1024;
    const short* Bg = Bm + (size_t)n0 * 1024;
    stage_tile(Ag, 1024, SH, tid);
    stage_tile(Bg, 1024, SH + 16384, tid);
    for (int it = 0; it < 16; ++it) {
        __syncthreads();                       // drains cur-buffer loads
        int cur = (it & 1) * 8192;
        short* Ac = SH + cur;
        short* Bc = SH + 16384 + cur;
        if (it + 1 < 16) {                     // prefetch next tile pair
            int nxt = ((it + 1) & 1) * 8192;
            stage_tile(Ag + (it + 1) * 64, 1024, SH + nxt, tid);
            stage_tile(Bg + (it + 1) * 64, 1024, SH + 16384 + nxt, tid);
        }
        COMPUTE_TILE(Ac, Bc);
    }
    short* outp = (which == 0) ? q : k;
    #pragma unroll
    for (int i = 0; i < 4; i++)
        #pragma unroll
        for (int j = 0; j < 4; j++)
            #pragma unroll
            for (int r = 0; r < 4; r++) {
                int row = m0 + wm + i*16 + lq*4 + r;     // m = b*2048+t
                int col = n0 + wn + j*16 + lr;           // e
                short hv = f2bf(acc[i][j][r]);
                if (which == 2) {
                    int bb = row >> 11, t = row & 2047;
                    vt[((size_t)bb << 21) + ((size_t)col << 11) + t] = hv;
                } else {
                    outp[(size_t)row * 1024 + col] = hv;
                }
            }
}

// ---------------------------------------------------------------- tile suffix sums
__global__ void k_ts1(const short* __restrict__ vt, float* __restrict__ TSpart) {
    int g = blockIdx.x * 256 + threadIdx.x;           // 4*16*1024 threads
    int b = g >> 14, jt = (g >> 10) & 15, e = g & 1023;
    const short* row = vt + ((size_t)b << 21) + ((size_t)e << 11) + jt * 128;
    float s = 0.f;
    #pragma unroll
    for (int c = 0; c < 16; c++) {
        uint4 u = *(const uint4*)(row + c * 8);
        const short* hp = (const short*)&u;
        #pragma unroll
        for (int z = 0; z < 8; z++) s += bf2f(hp[z]);
    }
    TSpart[g] = s;   // [b][jt][e]
}
__global__ void k_ts2(const float* __restrict__ TSpart, float* __restrict__ TS) {
    int g = blockIdx.x * 256 + threadIdx.x;           // 4*1024 threads
    int b = g >> 10, e = g & 1023;
    float acc = 0.f;
    TS[(size_t)(b * 17 + 16) * 1024 + e] = 0.f;
    for (int jt = 15; jt >= 0; jt--) {
        acc += TSpart[(size_t)(b * 16 + jt) * 1024 + e];
        TS[(size_t)(b * 17 + jt) * 1024 + e] = acc;   // sum over j >= jt*128
    }
}

// ---------------------------------------------------------------- S -> P kernel (dbuf, compact grid)
__global__ __launch_bounds__(256) void k_pk(const short* __restrict__ qm,
                                            const short* __restrict__ km,
                                            short* __restrict__ P,
                                            float* __restrict__ rowsum) {
    int idx = blockIdx.x, b = blockIdx.z;
    int qt = 0;
    while ((qt + 1) * (qt + 2) / 2 <= idx) qt++;
    int kt = idx - qt * (qt + 1) / 2;
    const short* Ag = qm + ((size_t)b * 2048 + (size_t)qt * 128) * 1024;
    const short* Bg = km + ((size_t)b * 2048 + (size_t)kt * 128) * 1024;
    __shared__ __align__(16) short SH[32768];
    int tid = threadIdx.x, lane = tid & 63, wave = tid >> 6;
    int wm = (wave >> 1) * 64, wn = (wave & 1) * 64;
    int lr = lane & 15, lq = lane >> 4;
    v4f acc[4][4];
    for (int i = 0; i < 4; i++) for (int j = 0; j < 4; j++) acc[i][j] = (v4f){0.f,0.f,0.f,0.f};

    stage_tile(Ag, 1024, SH, tid);
    stage_tile(Bg, 1024, SH + 16384, tid);
    for (int it = 0; it < 16; ++it) {
        __syncthreads();
        int cur = (it & 1) * 8192;
        short* Ac = SH + cur;
        short* Bc = SH + 16384 + cur;
        if (it + 1 < 16) {
            int nxt = ((it + 1) & 1) * 8192;
            stage_tile(Ag + (it + 1) * 64, 1024, SH + nxt, tid);
            stage_tile(Bg + (it + 1) * 64, 1024, SH + 16384 + nxt, tid);
        }
        COMPUTE_TILE(Ac, Bc);
    }
    short* Pb = P + ((size_t)b << 22);
    float rs[4][4];
    for (int i = 0; i < 4; i++) for (int r = 0; r < 4; r++) rs[i][r] = 0.f;
    #pragma unroll
    for (int i = 0; i < 4; i++)
        #pragma unroll
        for (int j = 0; j < 4; j++)
            #pragma unroll
            for (int r = 0; r < 4; r++) {
                int qi = qt * 128 + wm + i*16 + lq*4 + r;
                int kj = kt * 128 + wn + j*16 + lr;
                float p = (kj <= qi) ? __expf(acc[i][j][r] * SCALE) : 1.0f;
                Pb[(size_t)qi * 2048 + kj] = f2bf(p);
                rs[i][r] += p;
            }
    #pragma unroll
    for (int m = 1; m < 16; m <<= 1)
        #pragma unroll
        for (int i = 0; i < 4; i++)
            #pragma unroll
            for (int r = 0; r < 4; r++) rs[i][r] += __shfl_xor(rs[i][r], m);
    if (lr == 0)
        #pragma unroll
        for (int i = 0; i < 4; i++)
            #pragma unroll
            for (int r = 0; r < 4; r++)
                atomicAdd(&rowsum[b * 2048 + qt * 128 + wm + i*16 + lq*4 + r], rs[i][r]);
}

// ---------------------------------------------------------------- PV kernel (paired qt, uniform 34 iters)
__global__ __launch_bounds__(256) void k_pv(const short* __restrict__ P,
                                            const short* __restrict__ vt,
                                            const float* __restrict__ rowsum,
                                            const float* __restrict__ TS,
                                            float* __restrict__ out) {
    int et = blockIdx.x, p = blockIdx.y, b = blockIdx.z;
    const short* Bg = vt + ((size_t)b << 21) + (size_t)et * 128 * 2048;  // rows e, ld 2048
    __shared__ __align__(16) short SH[32768];
    int tid = threadIdx.x, lane = tid & 63, wave = tid >> 6;
    int wm = (wave >> 1) * 64, wn = (wave & 1) * 64;
    int lr = lane & 15, lq = lane >> 4;

    #pragma unroll
    for (int ph = 0; ph < 2; ph++) {
        int qt = ph ? p : 15 - p;              // (15-p) then p: 2(qt+1) sums to 34 iters
        int iters = 2 * (qt + 1);
        const short* Ag = P + ((size_t)b << 22) + (size_t)qt * 128 * 2048;  // rows i, ld 2048
        v4f acc[4][4];
        for (int i = 0; i < 4; i++) for (int j = 0; j < 4; j++) acc[i][j] = (v4f){0.f,0.f,0.f,0.f};

        stage_tile(Ag, 2048, SH, tid);
        stage_tile(Bg, 2048, SH + 16384, tid);
        for (int it = 0; it < iters; ++it) {
            __syncthreads();
            int cur = (it & 1) * 8192;
            short* Ac = SH + cur;
            short* Bc = SH + 16384 + cur;
            if (it + 1 < iters) {
                int nxt = ((it + 1) & 1) * 8192;
                stage_tile(Ag + (it + 1) * 64, 2048, SH + nxt, tid);
                stage_tile(Bg + (it + 1) * 64, 2048, SH + 16384 + nxt, tid);
            }
            COMPUTE_TILE(Ac, Bc);
        }
        const float* tsrow = TS + (size_t)(b * 17 + qt + 1) * 1024;
        #pragma unroll
        for (int i = 0; i < 4; i++)
            #pragma unroll
            for (int j = 0; j < 4; j++)
                #pragma unroll
                for (int r = 0; r < 4; r++) {
                    int row = qt * 128 + wm + i*16 + lq*4 + r;
                    int col = et * 128 + wn + j*16 + lr;
                    float o = (acc[i][j][r] + tsrow[col]) / rowsum[b * 2048 + row];
                    out[((size_t)(b * 2048 + row) << 10) + col] = o;
                }
        __syncthreads();   // protect LDS before next phase's initial staging
    }
}

// ---------------------------------------------------------------- launch
extern "C" void kernel_launch(void* const* d_in, const int* in_sizes, int n_in,
                              void* d_out, int out_size, void* d_ws, size_t ws_size,
                              hipStream_t stream) {
    const float* x  = (const float*)d_in[0];
    const float* Wq = (const float*)d_in[1];
    const float* Wk = (const float*)d_in[2];
    const float* Wv = (const float*)d_in[3];
    float* out = (float*)d_out;
    char* ws = (char*)d_ws;

    short* xb     = (short*)(ws + 0);            // 16,777,216 B
    short* wb     = (short*)(ws + 16777216);     //  6,291,456 B (Wq|Wk|Wv bf16)
    short* q      = (short*)(ws + 23068672);     // 16,777,216 B
    short* k      = (short*)(ws + 39845888);     // 16,777,216 B
    short* vt     = (short*)(ws + 56623104);     // 16,777,216 B  v transposed [b][e][t]
    short* P      = (short*)(ws + 73400320);     // 33,554,432 B
    float* rowsum = (float*)(ws + 106954752);    //     32,768 B
    float* TSpart = (float*)(ws + 106987520);    //    262,144 B
    float* TS     = (float*)(ws + 107249664);    //    278,528 B   total ~102.6 MB

    k_convert<<<11264, 256, 0, stream>>>(x, Wq, Wk, Wv, xb, rowsum);
    k_qkv<<<dim3(64, 8, 3), 256, 0, stream>>>(xb, wb, q, k, vt);
    k_ts1<<<256, 256, 0, stream>>>(vt, TSpart);
    k_ts2<<<16, 256, 0, stream>>>(TSpart, TS);
    k_pk<<<dim3(136, 1, 4), 256, 0, stream>>>(q, k, P, rowsum);
    k_pv<<<dim3(8, 8, 4), 256, 0, stream>>>(P, vt, rowsum, TS, out);
}

// Round 7
// 238.191 us; speedup vs baseline: 1.2736x; 1.0507x over previous
//
#include <hip/hip_runtime.h>
#include <stdint.h>

#define BB 4
#define TT 2048
#define DD 1024
#define NX (BB*TT*DD)          /* 8388608 x elements   */
#define NW (DD*DD)             /* 1048576 per W        */
#define SCALE 0.022097086912079608f   /* 1/sqrt(2048) */

typedef short v8s __attribute__((ext_vector_type(8)));
typedef float v4f __attribute__((ext_vector_type(4)));

typedef const void __attribute__((address_space(1))) *as1_cvp;
typedef void __attribute__((address_space(3))) *as3_vp;

__device__ __forceinline__ short f2bf(float f) {
    union { float f; uint32_t u; } x; x.f = f;
    uint32_t r = x.u + 0x7fffu + ((x.u >> 16) & 1u);   // RNE, finite inputs
    return (short)(r >> 16);
}
__device__ __forceinline__ float bf2f(short s) {
    union { uint32_t u; float f; } x; x.u = ((uint32_t)(uint16_t)s) << 16;
    return x.f;
}

// Async 16B global->LDS. lds dest must be wave-uniform base + lane*16.
__device__ __forceinline__ void gl_lds16(const short* g, const short* lds_wave_base) {
    __builtin_amdgcn_global_load_lds(
        (as1_cvp)(uintptr_t)(const void*)g,
        (as3_vp)(uint32_t)(uintptr_t)(const void*)lds_wave_base,
        16, 0, 0);
}

// ---- staging: rows x 64 shorts, XOR-8 chunk swizzle (row = 8 chunks = 32 banks)
__device__ __forceinline__ void stage_tile(const short* __restrict__ gsrc, int lda,
                                           short* lds, int tid) {     // 128 rows
    int wave = tid >> 6;
    #pragma unroll
    for (int is = 0; is < 4; is++) {
        int t = is * 256 + tid;          // 0..1023 : 16B chunk index
        int r = t >> 3, c = t & 7;
        int cg = c ^ (r & 7);            // swizzled global chunk
        const short* g = gsrc + (size_t)r * lda + cg * 8;
        const short* l = lds + is * 2048 + wave * 512;   // wave-uniform
        gl_lds16(g, l);
    }
}
__device__ __forceinline__ void stage_tile64(const short* __restrict__ gsrc, int lda,
                                             short* lds, int tid) {   // 64 rows
    int wave = tid >> 6;
    #pragma unroll
    for (int is = 0; is < 2; is++) {
        int t = is * 256 + tid;          // 0..511
        int r = t >> 3, c = t & 7;
        int cg = c ^ (r & 7);
        const short* g = gsrc + (size_t)r * lda + cg * 8;
        const short* l = lds + is * 2048 + wave * 512;
        gl_lds16(g, l);
    }
}
__device__ __forceinline__ v8s frag_read(const short* lds, int row, int cg) {
    return *(const v8s*)(lds + row * 64 + ((cg ^ (row & 7)) << 3));
}

// 128x128 tile compute (4 waves 2x2 of 64x64), acc[4][4]
#define COMPUTE_TILE(Ac, Bc)                                                        \
    _Pragma("unroll")                                                               \
    for (int kk = 0; kk < 2; kk++) {                                                \
        v8s af[4], bf[4];                                                           \
        _Pragma("unroll")                                                           \
        for (int i = 0; i < 4; i++) af[i] = frag_read(Ac, wm + i*16 + lr, kk*4 + lq); \
        _Pragma("unroll")                                                           \
        for (int j = 0; j < 4; j++) bf[j] = frag_read(Bc, wn + j*16 + lr, kk*4 + lq); \
        _Pragma("unroll")                                                           \
        for (int i = 0; i < 4; i++)                                                 \
            _Pragma("unroll")                                                       \
            for (int j = 0; j < 4; j++)                                             \
                acc[i][j] = __builtin_amdgcn_mfma_f32_16x16x32_bf16(af[i], bf[j], acc[i][j], 0, 0, 0); \
    }

// 64x128 tile compute (4 waves 2x2 of 32x64), acc[2][4]
#define COMPUTE_TILE64(Ac, Bc)                                                      \
    _Pragma("unroll")                                                               \
    for (int kk = 0; kk < 2; kk++) {                                                \
        v8s af[2], bf[4];                                                           \
        _Pragma("unroll")                                                           \
        for (int i = 0; i < 2; i++) af[i] = frag_read(Ac, wm + i*16 + lr, kk*4 + lq); \
        _Pragma("unroll")                                                           \
        for (int j = 0; j < 4; j++) bf[j] = frag_read(Bc, wn + j*16 + lr, kk*4 + lq); \
        _Pragma("unroll")                                                           \
        for (int i = 0; i < 2; i++)                                                 \
            _Pragma("unroll")                                                       \
            for (int j = 0; j < 4; j++)                                             \
                acc[i][j] = __builtin_amdgcn_mfma_f32_16x16x32_bf16(af[i], bf[j], acc[i][j], 0, 0, 0); \
    }

// ---------------------------------------------------------------- convert (+ rowsum init)
__global__ void k_convert(const float* __restrict__ x, const float* __restrict__ Wq,
                          const float* __restrict__ Wk, const float* __restrict__ Wv,
                          short* __restrict__ dst, float* __restrict__ rowsum) {
    int i = blockIdx.x * 256 + threadIdx.x;   // exactly (NX+3*NW)/4 threads
    if (i < BB * TT) rowsum[i] = (float)((15 - ((i & 2047) >> 7)) * 128);
    size_t base = (size_t)i * 4;
    const float* src; size_t off;
    if (base < NX)               { src = x;  off = base; }
    else if (base < NX + NW)     { src = Wq; off = base - NX; }
    else if (base < NX + 2*(size_t)NW) { src = Wk; off = base - NX - NW; }
    else                         { src = Wv; off = base - NX - 2*(size_t)NW; }
    float4 f = *(const float4*)(src + off);
    short4 h; h.x = f2bf(f.x); h.y = f2bf(f.y); h.z = f2bf(f.z); h.w = f2bf(f.w);
    *(short4*)(dst + base) = h;
}

// ---------------------------------------------------------------- QKV GEMM (BK=64 dbuf, 128x128)
__global__ __launch_bounds__(256) void k_qkv(const short* __restrict__ xb,
                                             const short* __restrict__ wb,
                                             short* __restrict__ q,
                                             short* __restrict__ k,
                                             short* __restrict__ vt) {
    int which = blockIdx.z;
    const short* Bm = wb + (size_t)which * NW;
    int m0 = blockIdx.x * 128, n0 = blockIdx.y * 128;
    __shared__ __align__(16) short SH[32768];   // A0|A1|B0|B1, 16KB each
    int tid = threadIdx.x, lane = tid & 63, wave = tid >> 6;
    int wm = (wave >> 1) * 64, wn = (wave & 1) * 64;
    int lr = lane & 15, lq = lane >> 4;
    v4f acc[4][4];
    for (int i = 0; i < 4; i++) for (int j = 0; j < 4; j++) acc[i][j] = (v4f){0.f,0.f,0.f,0.f};

    const short* Ag = xb + (size_t)m0 * 1024;
    const short* Bg = Bm + (size_t)n0 * 1024;
    stage_tile(Ag, 1024, SH, tid);
    stage_tile(Bg, 1024, SH + 16384, tid);
    for (int it = 0; it < 16; ++it) {
        __syncthreads();
        int cur = (it & 1) * 8192;
        short* Ac = SH + cur;
        short* Bc = SH + 16384 + cur;
        if (it + 1 < 16) {
            int nxt = ((it + 1) & 1) * 8192;
            stage_tile(Ag + (it + 1) * 64, 1024, SH + nxt, tid);
            stage_tile(Bg + (it + 1) * 64, 1024, SH + 16384 + nxt, tid);
        }
        COMPUTE_TILE(Ac, Bc);
    }
    short* outp = (which == 0) ? q : k;
    #pragma unroll
    for (int i = 0; i < 4; i++)
        #pragma unroll
        for (int j = 0; j < 4; j++)
            #pragma unroll
            for (int r = 0; r < 4; r++) {
                int row = m0 + wm + i*16 + lq*4 + r;     // m = b*2048+t
                int col = n0 + wn + j*16 + lr;           // e
                short hv = f2bf(acc[i][j][r]);
                if (which == 2) {
                    int bb = row >> 11, t = row & 2047;
                    vt[((size_t)bb << 21) + ((size_t)col << 11) + t] = hv;
                } else {
                    outp[(size_t)row * 1024 + col] = hv;
                }
            }
}

// ---------------------------------------------------------------- tile suffix sums
__global__ void k_ts1(const short* __restrict__ vt, float* __restrict__ TSpart) {
    int g = blockIdx.x * 256 + threadIdx.x;           // 4*16*1024 threads
    int b = g >> 14, jt = (g >> 10) & 15, e = g & 1023;
    const short* row = vt + ((size_t)b << 21) + ((size_t)e << 11) + jt * 128;
    float s = 0.f;
    #pragma unroll
    for (int c = 0; c < 16; c++) {
        uint4 u = *(const uint4*)(row + c * 8);
        const short* hp = (const short*)&u;
        #pragma unroll
        for (int z = 0; z < 8; z++) s += bf2f(hp[z]);
    }
    TSpart[g] = s;   // [b][jt][e]
}
__global__ void k_ts2(const float* __restrict__ TSpart, float* __restrict__ TS) {
    int g = blockIdx.x * 256 + threadIdx.x;           // 4*1024 threads
    int b = g >> 10, e = g & 1023;
    float acc = 0.f;
    TS[(size_t)(b * 17 + 16) * 1024 + e] = 0.f;
    for (int jt = 15; jt >= 0; jt--) {
        acc += TSpart[(size_t)(b * 16 + jt) * 1024 + e];
        TS[(size_t)(b * 17 + jt) * 1024 + e] = acc;   // sum over j >= jt*128
    }
}

// ---------------------------------------------------------------- S -> P kernel (BM=64, dbuf)
// grid.x = 272 (136 triangular pairs x 2 halves), big-qt first
__global__ __launch_bounds__(256, 3) void k_pk(const short* __restrict__ qm,
                                               const short* __restrict__ km,
                                               short* __restrict__ P,
                                               float* __restrict__ rowsum) {
    int flip = 271 - blockIdx.x, b = blockIdx.z;
    int half = flip & 1, pidx = flip >> 1;
    int qt = 0;
    while ((qt + 1) * (qt + 2) / 2 <= pidx) qt++;
    int kt = pidx - qt * (qt + 1) / 2;
    int r0 = qt * 128 + half * 64;                       // first q-row of this block
    const short* Ag = qm + ((size_t)b * 2048 + r0) * 1024;            // 64 rows
    const short* Bg = km + ((size_t)b * 2048 + (size_t)kt * 128) * 1024; // 128 rows
    __shared__ __align__(16) short SH[24576];            // A dbuf 2x8KB | B dbuf 2x16KB
    int tid = threadIdx.x, lane = tid & 63, wave = tid >> 6;
    int wm = (wave >> 1) * 32, wn = (wave & 1) * 64;
    int lr = lane & 15, lq = lane >> 4;
    v4f acc[2][4];
    for (int i = 0; i < 2; i++) for (int j = 0; j < 4; j++) acc[i][j] = (v4f){0.f,0.f,0.f,0.f};

    stage_tile64(Ag, 1024, SH, tid);
    stage_tile(Bg, 1024, SH + 8192, tid);
    for (int it = 0; it < 16; ++it) {
        __syncthreads();
        short* Ac = SH + (it & 1) * 4096;
        short* Bc = SH + 8192 + (it & 1) * 8192;
        if (it + 1 < 16) {
            stage_tile64(Ag + (it + 1) * 64, 1024, SH + ((it + 1) & 1) * 4096, tid);
            stage_tile  (Bg + (it + 1) * 64, 1024, SH + 8192 + ((it + 1) & 1) * 8192, tid);
        }
        COMPUTE_TILE64(Ac, Bc);
    }
    short* Pb = P + ((size_t)b << 22);
    float rs[2][4];
    for (int i = 0; i < 2; i++) for (int r = 0; r < 4; r++) rs[i][r] = 0.f;
    #pragma unroll
    for (int i = 0; i < 2; i++)
        #pragma unroll
        for (int j = 0; j < 4; j++)
            #pragma unroll
            for (int r = 0; r < 4; r++) {
                int qi = r0 + wm + i*16 + lq*4 + r;
                int kj = kt * 128 + wn + j*16 + lr;
                float p = (kj <= qi) ? __expf(acc[i][j][r] * SCALE) : 1.0f;
                Pb[(size_t)qi * 2048 + kj] = f2bf(p);
                rs[i][r] += p;
            }
    #pragma unroll
    for (int m = 1; m < 16; m <<= 1)
        #pragma unroll
        for (int i = 0; i < 2; i++)
            #pragma unroll
            for (int r = 0; r < 4; r++) rs[i][r] += __shfl_xor(rs[i][r], m);
    if (lr == 0)
        #pragma unroll
        for (int i = 0; i < 2; i++)
            #pragma unroll
            for (int r = 0; r < 4; r++)
                atomicAdd(&rowsum[b * 2048 + r0 + wm + i*16 + lq*4 + r], rs[i][r]);
}

// ---------------------------------------------------------------- PV kernel (BM=64, paired qt, 34 iters)
// grid = (8 et, 16 = 8 pairs x 2 halves, 4 b): 512 uniform blocks
__global__ __launch_bounds__(256, 3) void k_pv(const short* __restrict__ P,
                                               const short* __restrict__ vt,
                                               const float* __restrict__ rowsum,
                                               const float* __restrict__ TS,
                                               float* __restrict__ out) {
    int et = blockIdx.x, p = blockIdx.y >> 1, half = blockIdx.y & 1, b = blockIdx.z;
    const short* Bg = vt + ((size_t)b << 21) + (size_t)et * 128 * 2048;  // 128 e-rows, ld 2048
    __shared__ __align__(16) short SH[24576];            // A dbuf 2x8KB | B dbuf 2x16KB
    int tid = threadIdx.x, lane = tid & 63, wave = tid >> 6;
    int wm = (wave >> 1) * 32, wn = (wave & 1) * 64;
    int lr = lane & 15, lq = lane >> 4;

    #pragma unroll
    for (int ph = 0; ph < 2; ph++) {
        int qt = ph ? p : 15 - p;              // iters: 2(16-p) + 2(p+1) = 34 for all blocks
        int r0 = qt * 128 + half * 64;
        int iters = 2 * (qt + 1);
        const short* Ag = P + ((size_t)b << 22) + (size_t)r0 * 2048;   // 64 rows, ld 2048
        v4f acc[2][4];
        for (int i = 0; i < 2; i++) for (int j = 0; j < 4; j++) acc[i][j] = (v4f){0.f,0.f,0.f,0.f};

        stage_tile64(Ag, 2048, SH, tid);
        stage_tile(Bg, 2048, SH + 8192, tid);
        for (int it = 0; it < iters; ++it) {
            __syncthreads();
            short* Ac = SH + (it & 1) * 4096;
            short* Bc = SH + 8192 + (it & 1) * 8192;
            if (it + 1 < iters) {
                stage_tile64(Ag + (it + 1) * 64, 2048, SH + ((it + 1) & 1) * 4096, tid);
                stage_tile  (Bg + (it + 1) * 64, 2048, SH + 8192 + ((it + 1) & 1) * 8192, tid);
            }
            COMPUTE_TILE64(Ac, Bc);
        }
        const float* tsrow = TS + (size_t)(b * 17 + qt + 1) * 1024;
        #pragma unroll
        for (int i = 0; i < 2; i++)
            #pragma unroll
            for (int j = 0; j < 4; j++)
                #pragma unroll
                for (int r = 0; r < 4; r++) {
                    int row = r0 + wm + i*16 + lq*4 + r;
                    int col = et * 128 + wn + j*16 + lr;
                    float o = (acc[i][j][r] + tsrow[col]) / rowsum[b * 2048 + row];
                    out[((size_t)(b * 2048 + row) << 10) + col] = o;
                }
        __syncthreads();   // protect LDS before next phase's initial staging
    }
}

// ---------------------------------------------------------------- launch
extern "C" void kernel_launch(void* const* d_in, const int* in_sizes, int n_in,
                              void* d_out, int out_size, void* d_ws, size_t ws_size,
                              hipStream_t stream) {
    const float* x  = (const float*)d_in[0];
    const float* Wq = (const float*)d_in[1];
    const float* Wk = (const float*)d_in[2];
    const float* Wv = (const float*)d_in[3];
    float* out = (float*)d_out;
    char* ws = (char*)d_ws;

    short* xb     = (short*)(ws + 0);            // 16,777,216 B
    short* wb     = (short*)(ws + 16777216);     //  6,291,456 B (Wq|Wk|Wv bf16)
    short* q      = (short*)(ws + 23068672);     // 16,777,216 B
    short* k      = (short*)(ws + 39845888);     // 16,777,216 B
    short* vt     = (short*)(ws + 56623104);     // 16,777,216 B  v transposed [b][e][t]
    short* P      = (short*)(ws + 73400320);     // 33,554,432 B
    float* rowsum = (float*)(ws + 106954752);    //     32,768 B
    float* TSpart = (float*)(ws + 106987520);    //    262,144 B
    float* TS     = (float*)(ws + 107249664);    //    278,528 B   total ~102.6 MB

    k_convert<<<11264, 256, 0, stream>>>(x, Wq, Wk, Wv, xb, rowsum);
    k_qkv<<<dim3(64, 8, 3), 256, 0, stream>>>(xb, wb, q, k, vt);
    k_ts1<<<256, 256, 0, stream>>>(vt, TSpart);
    k_ts2<<<16, 256, 0, stream>>>(TSpart, TS);
    k_pk<<<dim3(272, 1, 4), 256, 0, stream>>>(q, k, P, rowsum);
    k_pv<<<dim3(8, 16, 4), 256, 0, stream>>>(P, vt, rowsum, TS, out);
}

// Round 8
// 230.394 us; speedup vs baseline: 1.3167x; 1.0338x over previous
//
#include <hip/hip_runtime.h>
#include <stdint.h>

#define BB 4
#define TT 2048
#define DD 1024
#define NX (BB*TT*DD)          /* 8388608 x elements   */
#define NW (DD*DD)             /* 1048576 per W        */
#define SCALE 0.022097086912079608f   /* 1/sqrt(2048) */

typedef short v8s __attribute__((ext_vector_type(8)));
typedef float v4f __attribute__((ext_vector_type(4)));

typedef const void __attribute__((address_space(1))) *as1_cvp;
typedef void __attribute__((address_space(3))) *as3_vp;

__device__ __forceinline__ short f2bf(float f) {
    union { float f; uint32_t u; } x; x.f = f;
    uint32_t r = x.u + 0x7fffu + ((x.u >> 16) & 1u);   // RNE, finite inputs
    return (short)(r >> 16);
}
__device__ __forceinline__ float bf2f(short s) {
    union { uint32_t u; float f; } x; x.u = ((uint32_t)(uint16_t)s) << 16;
    return x.f;
}

// Async 16B global->LDS. lds dest must be wave-uniform base + lane*16.
__device__ __forceinline__ void gl_lds16(const short* g, const short* lds_wave_base) {
    __builtin_amdgcn_global_load_lds(
        (as1_cvp)(uintptr_t)(const void*)g,
        (as3_vp)(uint32_t)(uintptr_t)(const void*)lds_wave_base,
        16, 0, 0);
}

// ---- staging: rows x 64 shorts, XOR-8 chunk swizzle (row = 8 chunks = 32 banks)
__device__ __forceinline__ void stage_tile(const short* __restrict__ gsrc, int lda,
                                           short* lds, int tid) {     // 128 rows
    int wave = tid >> 6;
    #pragma unroll
    for (int is = 0; is < 4; is++) {
        int t = is * 256 + tid;          // 0..1023 : 16B chunk index
        int r = t >> 3, c = t & 7;
        int cg = c ^ (r & 7);            // swizzled global chunk
        const short* g = gsrc + (size_t)r * lda + cg * 8;
        const short* l = lds + is * 2048 + wave * 512;   // wave-uniform
        gl_lds16(g, l);
    }
}
__device__ __forceinline__ void stage_tile64(const short* __restrict__ gsrc, int lda,
                                             short* lds, int tid) {   // 64 rows
    int wave = tid >> 6;
    #pragma unroll
    for (int is = 0; is < 2; is++) {
        int t = is * 256 + tid;          // 0..511
        int r = t >> 3, c = t & 7;
        int cg = c ^ (r & 7);
        const short* g = gsrc + (size_t)r * lda + cg * 8;
        const short* l = lds + is * 2048 + wave * 512;
        gl_lds16(g, l);
    }
}
__device__ __forceinline__ v8s frag_read(const short* lds, int row, int cg) {
    return *(const v8s*)(lds + row * 64 + ((cg ^ (row & 7)) << 3));
}

// 128x128 tile compute (4 waves 2x2 of 64x64), acc[4][4]
#define COMPUTE_TILE(Ac, Bc)                                                        \
    _Pragma("unroll")                                                               \
    for (int kk = 0; kk < 2; kk++) {                                                \
        v8s af[4], bf[4];                                                           \
        _Pragma("unroll")                                                           \
        for (int i = 0; i < 4; i++) af[i] = frag_read(Ac, wm + i*16 + lr, kk*4 + lq); \
        _Pragma("unroll")                                                           \
        for (int j = 0; j < 4; j++) bf[j] = frag_read(Bc, wn + j*16 + lr, kk*4 + lq); \
        _Pragma("unroll")                                                           \
        for (int i = 0; i < 4; i++)                                                 \
            _Pragma("unroll")                                                       \
            for (int j = 0; j < 4; j++)                                             \
                acc[i][j] = __builtin_amdgcn_mfma_f32_16x16x32_bf16(af[i], bf[j], acc[i][j], 0, 0, 0); \
    }

// 64x128 tile compute (4 waves 2x2 of 32x64), acc[2][4]
#define COMPUTE_TILE64(Ac, Bc)                                                      \
    _Pragma("unroll")                                                               \
    for (int kk = 0; kk < 2; kk++) {                                                \
        v8s af[2], bf[4];                                                           \
        _Pragma("unroll")                                                           \
        for (int i = 0; i < 2; i++) af[i] = frag_read(Ac, wm + i*16 + lr, kk*4 + lq); \
        _Pragma("unroll")                                                           \
        for (int j = 0; j < 4; j++) bf[j] = frag_read(Bc, wn + j*16 + lr, kk*4 + lq); \
        _Pragma("unroll")                                                           \
        for (int i = 0; i < 2; i++)                                                 \
            _Pragma("unroll")                                                       \
            for (int j = 0; j < 4; j++)                                             \
                acc[i][j] = __builtin_amdgcn_mfma_f32_16x16x32_bf16(af[i], bf[j], acc[i][j], 0, 0, 0); \
    }

// ---------------------------------------------------------------- convert (+ rowsum init)
__global__ void k_convert(const float* __restrict__ x, const float* __restrict__ Wq,
                          const float* __restrict__ Wk, const float* __restrict__ Wv,
                          short* __restrict__ dst, float* __restrict__ rowsum) {
    int i = blockIdx.x * 256 + threadIdx.x;   // exactly (NX+3*NW)/4 threads
    if (i < BB * TT) rowsum[i] = (float)((15 - ((i & 2047) >> 7)) * 128);
    size_t base = (size_t)i * 4;
    const float* src; size_t off;
    if (base < NX)               { src = x;  off = base; }
    else if (base < NX + NW)     { src = Wq; off = base - NX; }
    else if (base < NX + 2*(size_t)NW) { src = Wk; off = base - NX - NW; }
    else                         { src = Wv; off = base - NX - 2*(size_t)NW; }
    float4 f = *(const float4*)(src + off);
    short4 h; h.x = f2bf(f.x); h.y = f2bf(f.y); h.z = f2bf(f.z); h.w = f2bf(f.w);
    *(short4*)(dst + base) = h;
}

// ---------------------------------------------------------------- QKV GEMM (BK=64 dbuf, 128x128, FULL UNROLL)
__global__ __launch_bounds__(256) void k_qkv(const short* __restrict__ xb,
                                             const short* __restrict__ wb,
                                             short* __restrict__ q,
                                             short* __restrict__ k,
                                             short* __restrict__ vt) {
    int which = blockIdx.z;
    const short* Bm = wb + (size_t)which * NW;
    int m0 = blockIdx.x * 128, n0 = blockIdx.y * 128;
    __shared__ __align__(16) short SH[32768];   // A0|A1|B0|B1, 16KB each
    int tid = threadIdx.x, lane = tid & 63, wave = tid >> 6;
    int wm = (wave >> 1) * 64, wn = (wave & 1) * 64;
    int lr = lane & 15, lq = lane >> 4;
    v4f acc[4][4];
    for (int i = 0; i < 4; i++) for (int j = 0; j < 4; j++) acc[i][j] = (v4f){0.f,0.f,0.f,0.f};

    const short* Ag = xb + (size_t)m0 * 1024;
    const short* Bg = Bm + (size_t)n0 * 1024;
    stage_tile(Ag, 1024, SH, tid);
    stage_tile(Bg, 1024, SH + 16384, tid);
    #pragma unroll                              // compile-time offsets everywhere
    for (int it = 0; it < 16; ++it) {
        __syncthreads();
        short* Ac = SH + (it & 1) * 8192;
        short* Bc = SH + 16384 + (it & 1) * 8192;
        if (it + 1 < 16) {
            stage_tile(Ag + (it + 1) * 64, 1024, SH + ((it + 1) & 1) * 8192, tid);
            stage_tile(Bg + (it + 1) * 64, 1024, SH + 16384 + ((it + 1) & 1) * 8192, tid);
        }
        COMPUTE_TILE(Ac, Bc);
    }
    short* outp = (which == 0) ? q : k;
    #pragma unroll
    for (int i = 0; i < 4; i++)
        #pragma unroll
        for (int j = 0; j < 4; j++)
            #pragma unroll
            for (int r = 0; r < 4; r++) {
                int row = m0 + wm + i*16 + lq*4 + r;     // m = b*2048+t
                int col = n0 + wn + j*16 + lr;           // e
                short hv = f2bf(acc[i][j][r]);
                if (which == 2) {
                    int bb = row >> 11, t = row & 2047;
                    vt[((size_t)bb << 21) + ((size_t)col << 11) + t] = hv;
                } else {
                    outp[(size_t)row * 1024 + col] = hv;
                }
            }
}

// ---------------------------------------------------------------- tile suffix sums
__global__ void k_ts1(const short* __restrict__ vt, float* __restrict__ TSpart) {
    int g = blockIdx.x * 256 + threadIdx.x;           // 4*16*1024 threads
    int b = g >> 14, jt = (g >> 10) & 15, e = g & 1023;
    const short* row = vt + ((size_t)b << 21) + ((size_t)e << 11) + jt * 128;
    float s = 0.f;
    #pragma unroll
    for (int c = 0; c < 16; c++) {
        uint4 u = *(const uint4*)(row + c * 8);
        const short* hp = (const short*)&u;
        #pragma unroll
        for (int z = 0; z < 8; z++) s += bf2f(hp[z]);
    }
    TSpart[g] = s;   // [b][jt][e]
}
__global__ void k_ts2(const float* __restrict__ TSpart, float* __restrict__ TS) {
    int g = blockIdx.x * 256 + threadIdx.x;           // 4*1024 threads
    int b = g >> 10, e = g & 1023;
    float acc = 0.f;
    TS[(size_t)(b * 17 + 16) * 1024 + e] = 0.f;
    for (int jt = 15; jt >= 0; jt--) {
        acc += TSpart[(size_t)(b * 16 + jt) * 1024 + e];
        TS[(size_t)(b * 17 + jt) * 1024 + e] = acc;   // sum over j >= jt*128
    }
}

// ---------------------------------------------------------------- S -> P kernel (BM=64, dbuf, FULL UNROLL)
// grid.x = 272 (136 triangular pairs x 2 halves), big-qt first
__global__ __launch_bounds__(256, 3) void k_pk(const short* __restrict__ qm,
                                               const short* __restrict__ km,
                                               short* __restrict__ P,
                                               float* __restrict__ rowsum) {
    int flip = 271 - blockIdx.x, b = blockIdx.z;
    int half = flip & 1, pidx = flip >> 1;
    int qt = 0;
    while ((qt + 1) * (qt + 2) / 2 <= pidx) qt++;
    int kt = pidx - qt * (qt + 1) / 2;
    int r0 = qt * 128 + half * 64;                       // first q-row of this block
    const short* Ag = qm + ((size_t)b * 2048 + r0) * 1024;            // 64 rows
    const short* Bg = km + ((size_t)b * 2048 + (size_t)kt * 128) * 1024; // 128 rows
    __shared__ __align__(16) short SH[24576];            // A dbuf 2x8KB | B dbuf 2x16KB
    int tid = threadIdx.x, lane = tid & 63, wave = tid >> 6;
    int wm = (wave >> 1) * 32, wn = (wave & 1) * 64;
    int lr = lane & 15, lq = lane >> 4;
    v4f acc[2][4];
    for (int i = 0; i < 2; i++) for (int j = 0; j < 4; j++) acc[i][j] = (v4f){0.f,0.f,0.f,0.f};

    stage_tile64(Ag, 1024, SH, tid);
    stage_tile(Bg, 1024, SH + 8192, tid);
    #pragma unroll
    for (int it = 0; it < 16; ++it) {
        __syncthreads();
        short* Ac = SH + (it & 1) * 4096;
        short* Bc = SH + 8192 + (it & 1) * 8192;
        if (it + 1 < 16) {
            stage_tile64(Ag + (it + 1) * 64, 1024, SH + ((it + 1) & 1) * 4096, tid);
            stage_tile  (Bg + (it + 1) * 64, 1024, SH + 8192 + ((it + 1) & 1) * 8192, tid);
        }
        COMPUTE_TILE64(Ac, Bc);
    }
    short* Pb = P + ((size_t)b << 22);
    float rs[2][4];
    for (int i = 0; i < 2; i++) for (int r = 0; r < 4; r++) rs[i][r] = 0.f;
    #pragma unroll
    for (int i = 0; i < 2; i++)
        #pragma unroll
        for (int j = 0; j < 4; j++)
            #pragma unroll
            for (int r = 0; r < 4; r++) {
                int qi = r0 + wm + i*16 + lq*4 + r;
                int kj = kt * 128 + wn + j*16 + lr;
                float p = (kj <= qi) ? __expf(acc[i][j][r] * SCALE) : 1.0f;
                Pb[(size_t)qi * 2048 + kj] = f2bf(p);
                rs[i][r] += p;
            }
    #pragma unroll
    for (int m = 1; m < 16; m <<= 1)
        #pragma unroll
        for (int i = 0; i < 2; i++)
            #pragma unroll
            for (int r = 0; r < 4; r++) rs[i][r] += __shfl_xor(rs[i][r], m);
    if (lr == 0)
        #pragma unroll
        for (int i = 0; i < 2; i++)
            #pragma unroll
            for (int r = 0; r < 4; r++)
                atomicAdd(&rowsum[b * 2048 + r0 + wm + i*16 + lq*4 + r], rs[i][r]);
}

// ---------------------------------------------------------------- PV kernel (BM=64, paired qt, 34 iters, UNROLL 2)
// grid = (8 et, 16 = 8 pairs x 2 halves, 4 b): 512 uniform blocks
__global__ __launch_bounds__(256, 3) void k_pv(const short* __restrict__ P,
                                               const short* __restrict__ vt,
                                               const float* __restrict__ rowsum,
                                               const float* __restrict__ TS,
                                               float* __restrict__ out) {
    int et = blockIdx.x, p = blockIdx.y >> 1, half = blockIdx.y & 1, b = blockIdx.z;
    const short* Bg = vt + ((size_t)b << 21) + (size_t)et * 128 * 2048;  // 128 e-rows, ld 2048
    __shared__ __align__(16) short SH[24576];            // A dbuf 2x8KB | B dbuf 2x16KB
    int tid = threadIdx.x, lane = tid & 63, wave = tid >> 6;
    int wm = (wave >> 1) * 32, wn = (wave & 1) * 64;
    int lr = lane & 15, lq = lane >> 4;

    #pragma unroll
    for (int ph = 0; ph < 2; ph++) {
        int qt = ph ? p : 15 - p;              // iters: 2(16-p) + 2(p+1) = 34 for all blocks
        int r0 = qt * 128 + half * 64;
        int iters = 2 * (qt + 1);              // always even
        const short* Ag = P + ((size_t)b << 22) + (size_t)r0 * 2048;   // 64 rows, ld 2048
        v4f acc[2][4];
        for (int i = 0; i < 2; i++) for (int j = 0; j < 4; j++) acc[i][j] = (v4f){0.f,0.f,0.f,0.f};

        stage_tile64(Ag, 2048, SH, tid);
        stage_tile(Bg, 2048, SH + 8192, tid);
        for (int it = 0; it < iters; it += 2) {
            // ---- even sub-iter: buffers 0, prefetch into buffers 1
            __syncthreads();
            if (it + 1 < iters) {
                stage_tile64(Ag + (it + 1) * 64, 2048, SH + 4096, tid);
                stage_tile  (Bg + (it + 1) * 64, 2048, SH + 8192 + 8192, tid);
            }
            COMPUTE_TILE64(SH, SH + 8192);
            // ---- odd sub-iter: buffers 1, prefetch into buffers 0
            __syncthreads();
            if (it + 2 < iters) {
                stage_tile64(Ag + (it + 2) * 64, 2048, SH, tid);
                stage_tile  (Bg + (it + 2) * 64, 2048, SH + 8192, tid);
            }
            COMPUTE_TILE64(SH + 4096, SH + 8192 + 8192);
        }
        const float* tsrow = TS + (size_t)(b * 17 + qt + 1) * 1024;
        #pragma unroll
        for (int i = 0; i < 2; i++)
            #pragma unroll
            for (int j = 0; j < 4; j++)
                #pragma unroll
                for (int r = 0; r < 4; r++) {
                    int row = r0 + wm + i*16 + lq*4 + r;
                    int col = et * 128 + wn + j*16 + lr;
                    float o = (acc[i][j][r] + tsrow[col]) / rowsum[b * 2048 + row];
                    out[((size_t)(b * 2048 + row) << 10) + col] = o;
                }
        __syncthreads();   // protect LDS before next phase's initial staging
    }
}

// ---------------------------------------------------------------- launch
extern "C" void kernel_launch(void* const* d_in, const int* in_sizes, int n_in,
                              void* d_out, int out_size, void* d_ws, size_t ws_size,
                              hipStream_t stream) {
    const float* x  = (const float*)d_in[0];
    const float* Wq = (const float*)d_in[1];
    const float* Wk = (const float*)d_in[2];
    const float* Wv = (const float*)d_in[3];
    float* out = (float*)d_out;
    char* ws = (char*)d_ws;

    short* xb     = (short*)(ws + 0);            // 16,777,216 B
    short* wb     = (short*)(ws + 16777216);     //  6,291,456 B (Wq|Wk|Wv bf16)
    short* q      = (short*)(ws + 23068672);     // 16,777,216 B
    short* k      = (short*)(ws + 39845888);     // 16,777,216 B
    short* vt     = (short*)(ws + 56623104);     // 16,777,216 B  v transposed [b][e][t]
    short* P      = (short*)(ws + 73400320);     // 33,554,432 B
    float* rowsum = (float*)(ws + 106954752);    //     32,768 B
    float* TSpart = (float*)(ws + 106987520);    //    262,144 B
    float* TS     = (float*)(ws + 107249664);    //    278,528 B   total ~102.6 MB

    k_convert<<<11264, 256, 0, stream>>>(x, Wq, Wk, Wv, xb, rowsum);
    k_qkv<<<dim3(64, 8, 3), 256, 0, stream>>>(xb, wb, q, k, vt);
    k_ts1<<<256, 256, 0, stream>>>(vt, TSpart);
    k_ts2<<<16, 256, 0, stream>>>(TSpart, TS);
    k_pk<<<dim3(272, 1, 4), 256, 0, stream>>>(q, k, P, rowsum);
    k_pv<<<dim3(8, 16, 4), 256, 0, stream>>>(P, vt, rowsum, TS, out);
}